// Round 3
// baseline (339.819 us; speedup 1.0000x reference)
//
#include <hip/hip_runtime.h>

// SoftDecisionTree fused pipeline for MI355X (gfx950).
// Inputs: x[16384,2048] f32, y[16384,1000] f32 one-hot, W[255,2048] f32,
//         b[255] f32, beta[255] f32, leaf_params[256,1000] f32
// Output: [loss(1) | output(16384*1000)] f32
//
// gemm_tree v3: BARRIER-FREE direct-to-register GEMM.
//  - r0/r1/r2 all stalled 5-8x above the memory floor because every
//    barrier-coupled staging phase exposed full memory latency to all waves
//    (2 blocks/CU, phase-correlated). v3 removes LDS staging and all barriers
//    from the K loop: each wave loads A fragments straight from x (16 rows x
//    128 B contiguous per instruction pair, x streamed once) and B fragments
//    from the L2-resident fragment-major WbP. 4-deep named-register pipeline.
//  - Single __syncthreads before the (unchanged) fused sigmoid+tree epilogue.
//  - Load values, cvt rounding, per-element k-order, and the accA/accB
//    half-split are bit-identical to the verified r1/r2 kernels.

typedef __attribute__((ext_vector_type(8))) short short8;
typedef __attribute__((ext_vector_type(4))) float f32x4;

#define DIM 2048
#define NCLS 1000
#define NINNER 255
#define NPAD 256
#define BM 32        // rows per block (wave tile 32x64, 4 waves cover N=256)

__device__ __forceinline__ unsigned cvt2bf(float a, float b) {
  // round-half-up fp32 -> bf16, packed pair (identical to verified baseline)
  return ((__float_as_uint(a) + 0x8000u) >> 16) | ((__float_as_uint(b) + 0x8000u) & 0xFFFF0000u);
}

// W -> fragment-major bf16: WbP[((kt*16 + T)*64 + lane)*8 + e] =
//   bf16(W[T*16 + (lane&15)][kt*32 + (lane>>4)*8 + e]);  row 255 zero pad.
__global__ __launch_bounds__(256) void prep_w(const float* __restrict__ W,
                                              const float* __restrict__ b,
                                              const float* __restrict__ beta,
                                              unsigned short* __restrict__ WbP,
                                              float* __restrict__ bp,
                                              float* __restrict__ betap) {
  int f = blockIdx.x * 256 + threadIdx.x;  // 0..65535 fragments
  int kt = f >> 10;
  int T = (f >> 6) & 15;
  int l = f & 63;
  int row = T * 16 + (l & 15);
  int k0 = kt * 32 + (l >> 4) * 8;
  uint4 o = make_uint4(0u, 0u, 0u, 0u);
  if (row < NINNER) {
    const float* src = W + (size_t)row * DIM + k0;
    o.x = cvt2bf(src[0], src[1]);
    o.y = cvt2bf(src[2], src[3]);
    o.z = cvt2bf(src[4], src[5]);
    o.w = cvt2bf(src[6], src[7]);
  }
  *(uint4*)(WbP + (size_t)f * 8) = o;
  if (f < NPAD) {
    bp[f] = (f < NINNER) ? b[f] : 0.f;
    betap[f] = (f < NINNER) ? beta[f] : 0.f;
  }
}

__global__ __launch_bounds__(256) void leaf_softmax(const float* __restrict__ leaf,
                                                    float* __restrict__ logQT,
                                                    float* __restrict__ Q) {
  int l = blockIdx.x, t = threadIdx.x;
  const float* row = leaf + (size_t)l * NCLS;
  __shared__ float red[256];
  float mx = -3.4e38f;
  for (int j = t; j < NCLS; j += 256) mx = fmaxf(mx, row[j]);
  red[t] = mx; __syncthreads();
  for (int s = 128; s; s >>= 1) { if (t < s) red[t] = fmaxf(red[t], red[t + s]); __syncthreads(); }
  mx = red[0]; __syncthreads();
  float sm = 0.f;
  for (int j = t; j < NCLS; j += 256) sm += __expf(row[j] - mx);
  red[t] = sm; __syncthreads();
  for (int s = 128; s; s >>= 1) { if (t < s) red[t] += red[t + s]; __syncthreads(); }
  float lse = mx + __logf(red[0]);
  for (int j = t; j < NCLS; j += 256) {
    float lg = row[j] - lse;
    logQT[(size_t)j * NPAD + l] = lg;      // transposed: [class][leaf]
    Q[(size_t)l * NCLS + j] = __expf(lg);
  }
}

__global__ __launch_bounds__(256) void find_targets(const float* __restrict__ y,
                                                    int* __restrict__ tgt) {
  int wv = threadIdx.x >> 6, lane = threadIdx.x & 63;
  int r = blockIdx.x * 4 + wv;
  const float4* yr = (const float4*)(y + (size_t)r * NCLS);
  int found = 0x7fffffff;
#pragma unroll
  for (int i = 0; i < 4; ++i) {
    int j4 = i * 64 + lane;
    if (j4 < 250) {
      float4 v = yr[j4];
      if (v.x > 0.5f) found = min(found, 4 * j4 + 0);
      if (v.y > 0.5f) found = min(found, 4 * j4 + 1);
      if (v.z > 0.5f) found = min(found, 4 * j4 + 2);
      if (v.w > 0.5f) found = min(found, 4 * j4 + 3);
    }
  }
  for (int off = 32; off; off >>= 1) found = min(found, __shfl_down(found, off));
  if (lane == 0) tgt[r] = found;
}

// ---- direct-to-register GEMM pipeline stages (named sets, rule #20) ----
// Per k-step (32 k): A = 2 rows-of-16 x 32 B/lane (4x float4), B = 4 frags (short8).
#define DECLF(S) float4 S##a00, S##a01, S##a10, S##a11; short8 S##b0, S##b1, S##b2, S##b3;

#define LOADK(S, kt) do {                                                    \
  const float* _a0 = arow0 + (size_t)(kt) * 32;                              \
  const float* _a1 = arow1 + (size_t)(kt) * 32;                              \
  S##a00 = *(const float4*)_a0;  S##a01 = *(const float4*)(_a0 + 4);         \
  S##a10 = *(const float4*)_a1;  S##a11 = *(const float4*)(_a1 + 4);         \
  const unsigned short* _b = bptr + (size_t)(kt) * 8192;                     \
  S##b0 = *(const short8*)(_b);        S##b1 = *(const short8*)(_b + 512);   \
  S##b2 = *(const short8*)(_b + 1024); S##b3 = *(const short8*)(_b + 1536);  \
} while (0)

#define COMPUTE(S, AC) do {                                                  \
  short8 _afr0, _afr1;                                                       \
  { union { uint4 u; short8 s; } cv;                                         \
    cv.u.x = cvt2bf(S##a00.x, S##a00.y); cv.u.y = cvt2bf(S##a00.z, S##a00.w);\
    cv.u.z = cvt2bf(S##a01.x, S##a01.y); cv.u.w = cvt2bf(S##a01.z, S##a01.w);\
    _afr0 = cv.s; }                                                          \
  { union { uint4 u; short8 s; } cv;                                         \
    cv.u.x = cvt2bf(S##a10.x, S##a10.y); cv.u.y = cvt2bf(S##a10.z, S##a10.w);\
    cv.u.z = cvt2bf(S##a11.x, S##a11.y); cv.u.w = cvt2bf(S##a11.z, S##a11.w);\
    _afr1 = cv.s; }                                                          \
  AC[0][0] = __builtin_amdgcn_mfma_f32_16x16x32_bf16(_afr0, S##b0, AC[0][0], 0, 0, 0); \
  AC[1][0] = __builtin_amdgcn_mfma_f32_16x16x32_bf16(_afr1, S##b0, AC[1][0], 0, 0, 0); \
  AC[0][1] = __builtin_amdgcn_mfma_f32_16x16x32_bf16(_afr0, S##b1, AC[0][1], 0, 0, 0); \
  AC[1][1] = __builtin_amdgcn_mfma_f32_16x16x32_bf16(_afr1, S##b1, AC[1][1], 0, 0, 0); \
  AC[0][2] = __builtin_amdgcn_mfma_f32_16x16x32_bf16(_afr0, S##b2, AC[0][2], 0, 0, 0); \
  AC[1][2] = __builtin_amdgcn_mfma_f32_16x16x32_bf16(_afr1, S##b2, AC[1][2], 0, 0, 0); \
  AC[0][3] = __builtin_amdgcn_mfma_f32_16x16x32_bf16(_afr0, S##b3, AC[0][3], 0, 0, 0); \
  AC[1][3] = __builtin_amdgcn_mfma_f32_16x16x32_bf16(_afr1, S##b3, AC[1][3], 0, 0, 0); \
} while (0)

// Fused GEMM + sigmoid + tree walk. 512 blocks x 256 threads (4 waves), 2 blocks/CU.
// Wave tile 32x64 (wave n-quadrant); waves fully independent until the epilogue.
__global__ __launch_bounds__(256, 2) void gemm_tree(
    const float* __restrict__ x, const unsigned short* __restrict__ WbP,
    const float* __restrict__ bp, const float* __restrict__ betap,
    const float* __restrict__ logQT, const int* __restrict__ tgt,
    float* __restrict__ acc, int* __restrict__ best) {
  __shared__ __align__(16) float Ps[32 * 256];  // epilogue P tile (32 KB)
  __shared__ float s0s[127], s1s[127], sdot;

  int tid = threadIdx.x;
  int lane = tid & 63, wave = tid >> 6;
  int frow = lane & 15, fq = lane >> 4;
  int m_base = blockIdx.x * BM;

  if (tid < 127) { s0s[tid] = 0.f; s1s[tid] = 0.f; }
  if (tid == 255) sdot = 0.f;

  // A: lane reads rows (m_base+frow) and (+16), 32 B at k = kt*32 + fq*8 floats.
  const float* arow0 = x + (size_t)(m_base + frow) * DIM + fq * 8;
  const float* arow1 = arow0 + (size_t)16 * DIM;
  // B: wave's n-tiles T = wave*4 + nt (cols wave*64..+64), fragment-major.
  const unsigned short* bptr = WbP + ((size_t)wave * 256 + lane) * 8;

  f32x4 accA[2][4] = {}, accB[2][4] = {};

  DECLF(s0_) DECLF(s1_) DECLF(s2_) DECLF(s3_)
  LOADK(s0_, 0); LOADK(s1_, 1); LOADK(s2_, 2);

  for (int kt = 0; kt < 32; kt += 4) {  // k < 1024 half -> accA
    LOADK(s3_, kt + 3);
    COMPUTE(s0_, accA); LOADK(s0_, kt + 4);
    COMPUTE(s1_, accA); LOADK(s1_, kt + 5);
    COMPUTE(s2_, accA); LOADK(s2_, kt + 6);
    COMPUTE(s3_, accA);
  }
  for (int kt = 32; kt < 64; kt += 4) {  // k >= 1024 half -> accB
    LOADK(s3_, kt + 3);
    COMPUTE(s0_, accB); if (kt < 60) LOADK(s0_, kt + 4);
    COMPUTE(s1_, accB); if (kt < 60) LOADK(s1_, kt + 5);
    COMPUTE(s2_, accB); if (kt < 60) LOADK(s2_, kt + 6);
    COMPUTE(s3_, accB);
  }

  __syncthreads();  // only barrier before the epilogue

  // ---- fused epilogue: accumulators -> LDS P tile ----
#pragma unroll
  for (int mt = 0; mt < 2; ++mt)
#pragma unroll
    for (int nt = 0; nt < 4; ++nt)
#pragma unroll
      for (int rg = 0; rg < 4; ++rg)
        Ps[(mt * 16 + fq * 4 + rg) * 256 + wave * 64 + nt * 16 + frow] =
            accA[mt][nt][rg] + accB[mt][nt][rg];  // == (P0 + P1), same order as before
  __syncthreads();

  // sigmoid in place: thread owns column tid across all 32 rows
  {
    float bc2 = bp[tid], bec = betap[tid];
#pragma unroll 4
    for (int i = 0; i < 32; ++i) {
      float v = Ps[i * 256 + tid];
      Ps[i * 256 + tid] = 1.f / (1.f + __expf(-bec * (v + bc2)));
    }
  }
  __syncthreads();

  // tree walk: wave handles rows wave*8 .. +8; node sums accumulated in regs
  float wdot = 0.f;
  float s0r[7] = {}, s1r[7] = {};
  for (int it = 0; it < 8; ++it) {
    int rl = wave * 8 + it;
    int r = m_base + rl;
    const float* wsp = Ps + rl * 256;
    int tg = tgt[r];
    float pp = 1.f;  // path product into current depth
#pragma unroll
    for (int d = 1; d <= 6; ++d) {
      int idx = (1 << (d - 1)) - 1 + (lane >> (7 - d));
      float p = wsp[idx];
      s0r[d - 1] += pp;       // only first covering lane's value is used later
      s1r[d - 1] += p * pp;
      pp *= ((lane >> (6 - d)) & 1) ? p : (1.f - p);
    }
    float p7 = wsp[63 + lane];
    s0r[6] += pp;
    s1r[6] += p7 * pp;
    float pL = pp * (1.f - p7), pR = pp * p7;
    float p8a = wsp[127 + 2 * lane], p8b = wsp[128 + 2 * lane];
    float lf0 = pL * (1.f - p8a), lf1 = pL * p8a;
    float lf2 = pR * (1.f - p8b), lf3 = pR * p8b;
    float4 lq = *(const float4*)(logQT + (size_t)tg * NPAD + lane * 4);
    wdot += lf0 * lq.x + lf1 * lq.y + lf2 * lq.z + lf3 * lq.w;
    float bv = lf0; int bi = 4 * lane;
    if (lf1 > bv) { bv = lf1; bi = 4 * lane + 1; }
    if (lf2 > bv) { bv = lf2; bi = 4 * lane + 2; }
    if (lf3 > bv) { bv = lf3; bi = 4 * lane + 3; }
    for (int off = 32; off; off >>= 1) {
      float ov = __shfl_down(bv, off);
      int oi = __shfl_down(bi, off);
      if (ov > bv || (ov == bv && oi < bi)) { bv = ov; bi = oi; }  // first-max tie-break
    }
    if (lane == 0) best[r] = bi;
  }
  // fold per-wave node sums into block LDS arrays
#pragma unroll
  for (int d = 1; d <= 6; ++d) {
    int idx = (1 << (d - 1)) - 1 + (lane >> (7 - d));
    if ((lane & ((1 << (7 - d)) - 1)) == 0) {
      atomicAdd(&s0s[idx], s0r[d - 1]);
      atomicAdd(&s1s[idx], s1r[d - 1]);
    }
  }
  atomicAdd(&s0s[63 + lane], s0r[6]);
  atomicAdd(&s1s[63 + lane], s1r[6]);
  for (int off = 32; off; off >>= 1) wdot += __shfl_down(wdot, off);
  if (lane == 0) atomicAdd(&sdot, wdot);
  __syncthreads();
  if (tid < 127) {
    atomicAdd(&acc[tid], s0s[tid]);
    atomicAdd(&acc[127 + tid], s1s[tid]);
  }
  if (tid == 255) atomicAdd(&acc[254], sdot);
}

__global__ __launch_bounds__(128) void finalize_loss(const float* __restrict__ acc,
                                                     float* __restrict__ out) {
  __shared__ float red[128];
  int t = threadIdx.x;
  float c = 0.f;
  if (t < 127) {
    float denom = acc[t];
    if (denom == 0.f) denom = 1e-6f;
    float alpha = acc[127 + t] / denom;
    alpha = fminf(fmaxf(alpha, 1e-6f), 1.f - 1e-6f);
    int d = 31 - __clz(t + 1) + 1;  // depth: idx 0 -> 1, idx 1..2 -> 2, ...
    float lm = 0.1f * exp2f(-(float)d);
    c = -lm * 0.5f * (logf(alpha) + log1pf(-alpha));
  }
  red[t] = c;
  __syncthreads();
  for (int s = 64; s; s >>= 1) { if (t < s) red[t] += red[t + s]; __syncthreads(); }
  if (t == 0) out[0] = -(acc[254] / 16384.f) + red[0];
}

__global__ __launch_bounds__(256) void gather_rows(const float* __restrict__ Q,
                                                   const int* __restrict__ best,
                                                   float* __restrict__ out) {
  int wv = threadIdx.x >> 6, lane = threadIdx.x & 63;
  int r = blockIdx.x * 4 + wv;
  const float* src = Q + (size_t)best[r] * NCLS;
  float* dst = out + 1 + (size_t)r * NCLS;  // rows start at global index 1+1000r
  if (lane < 3) dst[lane] = src[lane];
  if (lane == 0) dst[999] = src[999];
#pragma unroll
  for (int i = 0; i < 4; ++i) {
    int q = i * 64 + lane;
    if (q < 249) {
      int o = 3 + 4 * q;  // 16B-aligned in dst
      float4 v = make_float4(src[o], src[o + 1], src[o + 2], src[o + 3]);
      *(float4*)(dst + o) = v;
    }
  }
}

extern "C" void kernel_launch(void* const* d_in, const int* in_sizes, int n_in,
                              void* d_out, int out_size, void* d_ws, size_t ws_size,
                              hipStream_t stream) {
  const float* x = (const float*)d_in[0];
  const float* y = (const float*)d_in[1];
  const float* W = (const float*)d_in[2];
  const float* b = (const float*)d_in[3];
  const float* beta = (const float*)d_in[4];
  const float* leaf = (const float*)d_in[5];
  float* out = (float*)d_out;
  char* ws = (char*)d_ws;

  unsigned short* WbP = (unsigned short*)(ws + 0);       // 1048576 (fragment-major)
  float* bp    = (float*)(ws + 1048576);                 // 1024
  float* betap = (float*)(ws + 1049600);                 // 1024
  float* accb  = (float*)(ws + 1050624);                 // 1024 (255 used)
  int* tgt     = (int*)(ws + 1051648);                   // 65536
  int* best    = (int*)(ws + 1117184);                   // 65536
  float* logQT = (float*)(ws + 1182720);                 // 1000*256*4 = 1024000
  float* Q     = (float*)(ws + 2206720);                 // 1024000

  prep_w<<<256, 256, 0, stream>>>(W, b, beta, WbP, bp, betap);
  leaf_softmax<<<256, 256, 0, stream>>>(leaf, logQT, Q);
  find_targets<<<4096, 256, 0, stream>>>(y, tgt);
  hipMemsetAsync(accb, 0, 256 * sizeof(float), stream);
  gemm_tree<<<512, 256, 0, stream>>>(x, WbP, bp, betap, logQT, tgt, accb, best);
  finalize_loss<<<1, 128, 0, stream>>>(accb, out);
  gather_rows<<<4096, 256, 0, stream>>>(Q, best, out);
}